// Round 4
// baseline (590.903 us; speedup 1.0000x reference)
//
#include <hip/hip_runtime.h>
#include <hip/hip_bf16.h>
#include <math.h>

typedef __hip_bfloat16 bf16;
typedef short short8 __attribute__((ext_vector_type(8)));
typedef short short4v __attribute__((ext_vector_type(4)));
typedef float floatx4 __attribute__((ext_vector_type(4)));

constexpr int CB_ = 32;
constexpr int CT = 256;
constexpr int CF = 512;
constexpr int CN = 508;
constexpr int CM = 4;
constexpr int CT2 = 512;
constexpr int MROWS = CB_ * CF;  // 16384
constexpr int PADL = 528;

__device__ __forceinline__ float b2f(bf16 v) { return __bfloat162float(v); }
__device__ __forceinline__ bf16 f2b(float v) { return __float2bfloat16(v); }
__device__ __forceinline__ short f2s(float v) {
    bf16 t = __float2bfloat16(v);
    return __builtin_bit_cast(short, t);
}
__device__ __forceinline__ float silu_f(float x) { return x / (1.0f + __expf(-x)); }
__device__ __forceinline__ float softplus_f(float x) {
    return fmaxf(x, 0.0f) + __logf(1.0f + __expf(-fabsf(x)));
}

__device__ __forceinline__ void gl_lds16(const bf16* g, short* l) {
    __builtin_amdgcn_global_load_lds(
        (const __attribute__((address_space(1))) unsigned int*)(g),
        (__attribute__((address_space(3))) unsigned int*)(l), 16, 0, 0);
}

// BK=64 LDS tiles: [rows][64 shorts] (128B rows). gl_lds16 covers 8 rows x 64 cols.
// XOR swizzle: LDS slot (row, col16) holds global (row, col16 ^ (row&7)).
// Source addr per lane: row += lane>>3 ; col16 = (lane&7) ^ (lane>>3).
// ds_read col16' = (s*4+quad) ^ (row&7) recovers k = s*32 + quad*8.
// 2-phase pipeline: STAGE(buf^1, k+64) issued BEFORE COMPUTE(buf); single
// __syncthreads() per K-step (auto vmcnt-drain) => HBM latency hides under MFMA.

// ---- ALL prepack in one kernel: 8 weight transposes (+nw folding for inp/D),
// conv weight pack (float3/thread, coalesced), xpT pad rows, CBv zero.
constexpr int CONV3 = 3 * 512 * 512;  // 786432 (ib,co,ci) triples
constexpr int MTILES = 3520;
struct P8 { const float* s[8]; bf16* d[8]; };
__global__ __launch_bounds__(256) void prepack_all_kernel(P8 p, const float* __restrict__ nw,
                                                          const float* __restrict__ convW,
                                                          bf16* __restrict__ convD,
                                                          bf16* __restrict__ xpT,
                                                          float* __restrict__ CBv) {
    int bid = blockIdx.x;
    if (bid >= MTILES) {
        int idx = (bid - MTILES) * 256 + threadIdx.x;
        if (idx < CONV3) {
            int ci = idx & 511;
            int co = (idx >> 9) & 511;
            int ib = idx >> 18;
            const float* src = convW + ((size_t)(ib * 512 + co) * 512 + ci) * 3;
            #pragma unroll
            for (int t = 0; t < 3; t++)
                convD[(((size_t)(ib * 3 + t) * 512 + co) << 9) + ci] = f2b(src[t]);
        } else if (idx < CONV3 + 32768) {
            int j = idx - CONV3;
            int ci = j & 511;
            int w = (j >> 9) & 1;
            int b = j >> 10;
            xpT[((size_t)b * PADL + (w ? 513 : 0)) * 512 + ci] = f2b(0.0f);
        } else if (idx < CONV3 + 32768 + MROWS) {
            CBv[idx - CONV3 - 32768] = 0.0f;
        }
        return;
    }
    const int Ks[8]   = {256, 256, 512, 512, 512, 512, 512, 256};
    const int Ns[8]   = {512, 512, 512, 256, 256, 512, 256, 256};
    const int zs[8]   = {3, 3, 3, 3, 3, 3, 3, 1};
    const int dstr[8] = {262144, 262144, 524288, 524288, 524288, 262144, 131072, 65536};
    const int rml[8]  = {1, 1, 1, 2, 2, 1, 1, 1};
    const int rad[8]  = {0, 0, 0, 0, 1, 0, 0, 0};
    int m = 0, acc = 0;
    for (m = 0; m < 8; m++) {
        int c = (Ns[m] >> 5) * (Ks[m] >> 5) * zs[m];
        if (bid < acc + c) break;
        acc += c;
    }
    int lid = bid - acc;
    int K = Ks[m], N = Ns[m];
    int tx = N >> 5, ty = K >> 5;
    int z = lid / (tx * ty), rem = lid % (tx * ty);
    int k0 = (rem / tx) * 32, n0 = (rem % tx) * 32;
    const float* s = p.s[m] + (size_t)z * K * N;
    bf16* d = p.d[m] + (size_t)z * dstr[m];
    int mul = rml[m], add = rad[m];
    bool fold = (m <= 1);  // inp_W, D_W: fold nw_z into K-rows
    __shared__ float Ts[32][33];
    for (int e = threadIdx.x; e < 1024; e += 256) {
        int r = e >> 5, c = e & 31;
        float v = s[(size_t)(k0 + r) * N + n0 + c];
        if (fold) v *= nw[z * 256 + k0 + r];
        Ts[r][c] = v;
    }
    __syncthreads();
    for (int e = threadIdx.x; e < 1024; e += 256) {
        int r = e >> 5, c = e & 31;
        d[(size_t)((n0 + r) * mul + add) * K + k0 + c] = f2b(Ts[c][r]);
    }
}

// ---- fused stats + build_x (iter 0): writes RAW x (bf16) + rms scale SCL ----
__global__ __launch_bounds__(256) void buildx_kernel(
    const float* __restrict__ xe, const float* __restrict__ xm,
    float* __restrict__ means, float* __restrict__ stdev,
    bf16* __restrict__ X0, float* __restrict__ SCL) {
    __shared__ float L[256][65];
    __shared__ float red_s[4][64], red_q[4][64];
    __shared__ float stat_m[64], stat_i[64];
    int blk = blockIdx.x;
    int b = blk >> 3, f0 = (blk & 7) * 64;
    int tid = threadIdx.x;
    int j = tid & 63, tq = tid >> 6;
    int f = f0 + j;
    float ps = 0.f, pq = 0.f;
    const float* xep = xe + (size_t)b * CT * CN + f;
    const float* xmp = xm + (size_t)b * CT * CM + (f - CN);
    #pragma unroll 4
    for (int tt = 0; tt < 64; tt++) {
        int t = tq * 64 + tt;
        float v = (f < CN) ? xep[(size_t)t * CN] : xmp[(size_t)t * CM];
        L[t][j] = v;
        ps += v;
        pq += v * v;
    }
    red_s[tq][j] = ps;
    red_q[tq][j] = pq;
    __syncthreads();
    if (tid < 64) {
        int ff = f0 + tid;
        float s = red_s[0][tid] + red_s[1][tid] + red_s[2][tid] + red_s[3][tid];
        float q = red_q[0][tid] + red_q[1][tid] + red_q[2][tid] + red_q[3][tid];
        float mean, isd, msq;
        if (ff < CN) {
            mean = s * (1.0f / 256.0f);
            float var = fmaxf(q * (1.0f / 256.0f) - mean * mean, 0.0f);
            float sd = sqrtf(var + 1e-5f);
            isd = 1.0f / sd;
            means[b * CN + ff] = mean;
            stdev[b * CN + ff] = sd;
            msq = var / (var + 1e-5f);
        } else {
            mean = 0.0f;
            isd = 1.0f;
            msq = q * (1.0f / 256.0f);
        }
        stat_m[tid] = mean;
        stat_i[tid] = isd;
        SCL[b * 512 + ff] = rsqrtf(msq + 1e-5f);
    }
    __syncthreads();
    bf16* outp = X0 + ((size_t)(b * 512 + f0)) * 256;
    int t = tid;
    #pragma unroll 4
    for (int fp = 0; fp < 64; fp++) {
        float val = (L[t][fp] - stat_m[fp]) * stat_i[fp];
        outp[(size_t)fp * 256 + t] = f2b(val);
    }
}

// ---- unified 128x64-tile GEMM, BK=64, 2-phase double-buffered (48KB LDS).
// EPI 0: plain store (+b1). EPI 1: cb pair-product atomics (b1=fc2_b,b2=fc3_b).
// EPI 2: s6 gate (b1=fc1_b, CBin, Xres, o1=G). EPI 3: proj de-norm fp32 out.
// EPI 4: [inp|D]: n0<512 -> xpT scatter (b1, SCL); else silu->o2 (b2, SCL). ----
template <int EPI>
__global__ __launch_bounds__(256) void g64_kernel(const bf16* __restrict__ A,
                                                  const bf16* __restrict__ Wt,
                                                  int K,
                                                  const float* __restrict__ b1,
                                                  const float* __restrict__ b2,
                                                  const float* __restrict__ SCL,
                                                  const float* __restrict__ CBin,
                                                  const bf16* __restrict__ Xres,
                                                  float* __restrict__ CBout,
                                                  bf16* __restrict__ o1,
                                                  bf16* __restrict__ o2,
                                                  int Ncols,
                                                  const float* __restrict__ means,
                                                  const float* __restrict__ stdev,
                                                  float* __restrict__ outf) {
    __shared__ __align__(16) short As[2][128 * 64];
    __shared__ __align__(16) short Bs[2][64 * 64];
    const int tid = threadIdx.x;
    const int lane = tid & 63;
    const int wave = tid >> 6;
    const int m0 = blockIdx.x * 128, n0 = blockIdx.y * 64;

    const int lrow8 = lane >> 3;
    const int lcolS = (((lane & 7) ^ lrow8) << 3);
    const int wm = (wave & 1) * 64, wn = (wave >> 1) * 32;
    const int fr = lane & 15, quad = lane >> 4;
    const int fr7 = fr & 7;

    floatx4 acc[4][2];
    #pragma unroll
    for (int i = 0; i < 4; i++)
        #pragma unroll
        for (int j = 0; j < 2; j++) acc[i][j] = (floatx4){0.f, 0.f, 0.f, 0.f};

    auto STAGE = [&](int buf, int k0) {
        for (int ca = wave; ca < 16; ca += 4)
            gl_lds16(A + (size_t)(m0 + ca * 8 + lrow8) * K + k0 + lcolS, &As[buf][ca * 512]);
        for (int cb = wave; cb < 8; cb += 4)
            gl_lds16(Wt + (size_t)(n0 + cb * 8 + lrow8) * K + k0 + lcolS, &Bs[buf][cb * 512]);
    };
    auto COMPUTE = [&](int buf) {
        #pragma unroll
        for (int s = 0; s < 2; s++) {
            const int co = (((s * 4 + quad) ^ fr7) << 3);
            short8 af[4], bfv[2];
            #pragma unroll
            for (int i = 0; i < 4; i++) af[i] = *(const short8*)&As[buf][(wm + i * 16 + fr) * 64 + co];
            #pragma unroll
            for (int j = 0; j < 2; j++) bfv[j] = *(const short8*)&Bs[buf][(wn + j * 16 + fr) * 64 + co];
            #pragma unroll
            for (int i = 0; i < 4; i++)
                #pragma unroll
                for (int j = 0; j < 2; j++)
                    acc[i][j] = __builtin_amdgcn_mfma_f32_16x16x32_bf16(af[i], bfv[j], acc[i][j], 0, 0, 0);
        }
    };

    STAGE(0, 0);
    __syncthreads();
    int cur = 0;
    for (int k0 = 64; k0 < K; k0 += 64) {
        STAGE(cur ^ 1, k0);
        COMPUTE(cur);
        __syncthreads();
        cur ^= 1;
    }
    COMPUTE(cur);

    if (EPI == 0) {
        #pragma unroll
        for (int j = 0; j < 2; j++) {
            int n = n0 + wn + j * 16 + fr;
            float bv = b1[n];
            #pragma unroll
            for (int i = 0; i < 4; i++) {
                int mb = m0 + wm + i * 16 + quad * 4;
                #pragma unroll
                for (int r = 0; r < 4; r++)
                    o1[(size_t)(mb + r) * Ncols + n] = f2b(acc[i][j][r] + bv);
            }
        }
    } else if (EPI == 1) {
        float bv[2];
        #pragma unroll
        for (int j = 0; j < 2; j++) {
            int nn = n0 + wn + j * 16 + fr;
            int c = nn >> 1;
            bv[j] = (fr & 1) ? b2[c] : b1[c];
        }
        #pragma unroll
        for (int i = 0; i < 4; i++) {
            #pragma unroll
            for (int r = 0; r < 4; r++) {
                float s = 0.f;
                #pragma unroll
                for (int j = 0; j < 2; j++) {
                    float v = acc[i][j][r] + bv[j];
                    s += v * __shfl_xor(v, 1);
                }
                s += __shfl_xor(s, 2);
                s += __shfl_xor(s, 4);
                s += __shfl_xor(s, 8);
                if (fr == 0)
                    atomicAdd(&CBout[m0 + wm + i * 16 + quad * 4 + r], s * 0.5f);
            }
        }
    } else if (EPI == 2) {
        #pragma unroll
        for (int i = 0; i < 4; i++) {
            int mb = m0 + wm + i * 16 + quad * 4;
            float cbr[4];
            #pragma unroll
            for (int r = 0; r < 4; r++) cbr[r] = CBin[mb + r];
            #pragma unroll
            for (int j = 0; j < 2; j++) {
                int n = n0 + wn + j * 16 + fr;
                float bv = b1[n];
                #pragma unroll
                for (int r = 0; r < 4; r++) {
                    size_t off = (size_t)(mb + r) * 512 + n;
                    float delta = softplus_f(acc[i][j][r] + bv);
                    float xssm = delta * b2f(A[off]) * cbr[r];
                    o1[off] = f2b(silu_f(xssm) * b2f(Xres[off]));
                }
            }
        }
    } else if (EPI == 3) {  // proj + de-norm + transpose, fp32 out
        #pragma unroll
        for (int j = 0; j < 2; j++) {
            int t = n0 + wn + j * 16 + fr;
            float bv = b1[t];
            #pragma unroll
            for (int i = 0; i < 4; i++) {
                int mb = m0 + wm + i * 16 + quad * 4;
                int b = mb >> 9;
                int nv = mb & 511;
                if (nv < CN) {
                    floatx4 o;
                    #pragma unroll
                    for (int r = 0; r < 4; r++) {
                        int sn = b * CN + nv + r;
                        o[r] = (acc[i][j][r] + bv) * stdev[sn] + means[sn];
                    }
                    *(floatx4*)(outf + ((size_t)(b * CT + t)) * CN + nv) = o;
                }
            }
        }
    } else {  // EPI 4: [inp|D] with per-row rms scale
        if (n0 < 512) {
            int b = (m0 + wm) >> 9;
            #pragma unroll
            for (int i = 0; i < 4; i++) {
                int mb = m0 + wm + i * 16 + quad * 4;
                float sclr[4];
                #pragma unroll
                for (int r = 0; r < 4; r++) sclr[r] = SCL[mb + r];
                int ci = mb & 511;
                #pragma unroll
                for (int j = 0; j < 2; j++) {
                    int n = n0 + wn + j * 16 + fr;
                    float bv = b1[n];
                    bf16* dst = o1 + ((size_t)b * PADL + n + 1) * 512;
                    short4v pk;
                    #pragma unroll
                    for (int r = 0; r < 4; r++) pk[r] = f2s(acc[i][j][r] * sclr[r] + bv);
                    *(short4v*)(dst + ci) = pk;
                }
            }
        } else {
            #pragma unroll
            for (int i = 0; i < 4; i++) {
                int mb = m0 + wm + i * 16 + quad * 4;
                float sclr[4];
                #pragma unroll
                for (int r = 0; r < 4; r++) sclr[r] = SCL[mb + r];
                #pragma unroll
                for (int j = 0; j < 2; j++) {
                    int n = n0 + wn + j * 16 + fr;
                    float bv = b2[n - 512];
                    #pragma unroll
                    for (int r = 0; r < 4; r++)
                        o2[(size_t)(mb + r) * 512 + (n - 512)] =
                            f2b(silu_f(acc[i][j][r] * sclr[r] + bv));
                }
            }
        }
    }
}

// ---- conv as implicit MFMA GEMM, 64x64 tile, 2-phase dbuf (66KB LDS).
// Zeroes CBv at entry. ----
__global__ __launch_bounds__(256) void conv_mfma_kernel(const bf16* __restrict__ Wc,
                                                        const bf16* __restrict__ xpT,
                                                        const float* __restrict__ bias,
                                                        bf16* __restrict__ Out,
                                                        float* __restrict__ CBvZ) {
    __shared__ __align__(16) short As[2][3 * 64 * 64];
    __shared__ __align__(16) short Bs[2][72 * 64];
    const int tid = threadIdx.x;
    const int lane = tid & 63;
    const int wave = tid >> 6;
    int bx = blockIdx.x;
    if (bx < 128 && tid < 128) CBvZ[bx * 128 + tid] = 0.0f;
    int b = bx >> 6, rem = bx & 63;
    int mt = rem >> 3, nt = rem & 7;
    const int m0 = mt * 64, n0 = nt * 64;
    const bf16* xb = xpT + (size_t)b * PADL * 512;

    const int lrow8 = lane >> 3;
    const int lcolS = (((lane & 7) ^ lrow8) << 3);
    const int wm = (wave & 1) * 32, wn = (wave >> 1) * 32;
    const int fr = lane & 15, quad = lane >> 4;
    const int fr7 = fr & 7;

    floatx4 acc[2][2];
    #pragma unroll
    for (int i = 0; i < 2; i++)
        #pragma unroll
        for (int j = 0; j < 2; j++) acc[i][j] = (floatx4){0.f, 0.f, 0.f, 0.f};

    auto STAGE = [&](int buf, int k0) {
        for (int ga = wave; ga < 24; ga += 4) {
            int tap = ga >> 3, rg = ga & 7;
            gl_lds16(Wc + (size_t)tap * 262144 + (size_t)(m0 + rg * 8 + lrow8) * 512 + k0 + lcolS,
                     &As[buf][tap * 4096 + rg * 512]);
        }
        for (int gb = wave; gb < 9; gb += 4) {
            gl_lds16(xb + (size_t)(n0 + gb * 8 + lrow8) * 512 + k0 + lcolS, &Bs[buf][gb * 512]);
        }
    };
    auto COMPUTE = [&](int buf) {
        #pragma unroll
        for (int s = 0; s < 2; s++) {
            const int sq = s * 4 + quad;
            #pragma unroll
            for (int tap = 0; tap < 3; tap++) {
                const int coA = ((sq ^ fr7) << 3);
                const int coB = ((sq ^ ((fr + tap) & 7)) << 3);
                short8 af[2], bfv[2];
                #pragma unroll
                for (int i = 0; i < 2; i++)
                    af[i] = *(const short8*)&As[buf][tap * 4096 + (wm + i * 16 + fr) * 64 + coA];
                #pragma unroll
                for (int j = 0; j < 2; j++)
                    bfv[j] = *(const short8*)&Bs[buf][(wn + j * 16 + fr + tap) * 64 + coB];
                #pragma unroll
                for (int i = 0; i < 2; i++)
                    #pragma unroll
                    for (int j = 0; j < 2; j++)
                        acc[i][j] = __builtin_amdgcn_mfma_f32_16x16x32_bf16(af[i], bfv[j], acc[i][j], 0, 0, 0);
            }
        }
    };

    STAGE(0, 0);
    __syncthreads();
    int cur = 0;
    for (int k0 = 64; k0 < 512; k0 += 64) {
        STAGE(cur ^ 1, k0);
        COMPUTE(cur);
        __syncthreads();
        cur ^= 1;
    }
    COMPUTE(cur);

    bf16* ob = Out + (size_t)b * CF * CT2;
    #pragma unroll
    for (int i = 0; i < 2; i++) {
        int mb = m0 + wm + i * 16 + quad * 4;
        #pragma unroll
        for (int r = 0; r < 4; r++) {
            float bv = bias[mb + r];
            #pragma unroll
            for (int j = 0; j < 2; j++) {
                int n = n0 + wn + j * 16 + fr;
                ob[(size_t)(mb + r) * CT2 + n] = f2b(silu_f(acc[i][j][r] + bv));
            }
        }
    }
}

// ---- out-GEMM (K=512, N=256) + rms scale. M-tile 32, 2-phase dbuf (72KB). ----
__global__ __launch_bounds__(256) void gemm_scl_kernel(const bf16* __restrict__ A,
                                                       const bf16* __restrict__ Wt,
                                                       const float* __restrict__ bias,
                                                       bf16* __restrict__ Xo,
                                                       float* __restrict__ SCL) {
    __shared__ __align__(16) short As[2][32 * 64];
    __shared__ __align__(16) short Bs[2][256 * 64];
    __shared__ float red[4][32];
    const int tid = threadIdx.x;
    const int lane = tid & 63;
    const int wave = tid >> 6;
    const int m0 = blockIdx.x * 32;

    const int lrow8 = lane >> 3;
    const int lcolS = (((lane & 7) ^ lrow8) << 3);
    const int wn = wave * 64;
    const int fr = lane & 15, quad = lane >> 4;
    const int fr7 = fr & 7;

    floatx4 acc[2][4];
    #pragma unroll
    for (int i = 0; i < 2; i++)
        #pragma unroll
        for (int j = 0; j < 4; j++) acc[i][j] = (floatx4){0.f, 0.f, 0.f, 0.f};

    auto STAGE = [&](int buf, int k0) {
        for (int c = wave; c < 4; c += 4)
            gl_lds16(A + (size_t)(m0 + c * 8 + lrow8) * 512 + k0 + lcolS, &As[buf][c * 512]);
        for (int c = wave; c < 32; c += 4)
            gl_lds16(Wt + (size_t)(c * 8 + lrow8) * 512 + k0 + lcolS, &Bs[buf][c * 512]);
    };
    auto COMPUTE = [&](int buf) {
        #pragma unroll
        for (int s = 0; s < 2; s++) {
            const int co = (((s * 4 + quad) ^ fr7) << 3);
            short8 af[2], bfv[4];
            #pragma unroll
            for (int i = 0; i < 2; i++) af[i] = *(const short8*)&As[buf][(i * 16 + fr) * 64 + co];
            #pragma unroll
            for (int j = 0; j < 4; j++) bfv[j] = *(const short8*)&Bs[buf][(wn + j * 16 + fr) * 64 + co];
            #pragma unroll
            for (int i = 0; i < 2; i++)
                #pragma unroll
                for (int j = 0; j < 4; j++)
                    acc[i][j] = __builtin_amdgcn_mfma_f32_16x16x32_bf16(af[i], bfv[j], acc[i][j], 0, 0, 0);
        }
    };

    STAGE(0, 0);
    __syncthreads();
    int cur = 0;
    for (int k0 = 64; k0 < 512; k0 += 64) {
        STAGE(cur ^ 1, k0);
        COMPUTE(cur);
        __syncthreads();
        cur ^= 1;
    }
    COMPUTE(cur);

    #pragma unroll
    for (int j = 0; j < 4; j++) {
        float bv = bias[wn + j * 16 + fr];
        #pragma unroll
        for (int i = 0; i < 2; i++)
            #pragma unroll
            for (int r = 0; r < 4; r++) acc[i][j][r] += bv;
    }
    #pragma unroll
    for (int i = 0; i < 2; i++) {
        #pragma unroll
        for (int r = 0; r < 4; r++) {
            float s = 0.f;
            #pragma unroll
            for (int j = 0; j < 4; j++) s += acc[i][j][r] * acc[i][j][r];
            #pragma unroll
            for (int o = 8; o > 0; o >>= 1) s += __shfl_xor(s, o);
            if (fr == 0) red[wave][i * 16 + quad * 4 + r] = s;
        }
    }
    __syncthreads();
    if (tid < 32) {
        float tot = red[0][tid] + red[1][tid] + red[2][tid] + red[3][tid];
        SCL[m0 + tid] = rsqrtf(tot * (1.0f / CT) + 1e-5f);
    }
    #pragma unroll
    for (int j = 0; j < 4; j++) {
        int n = wn + j * 16 + fr;
        #pragma unroll
        for (int i = 0; i < 2; i++) {
            int rl = i * 16 + quad * 4;
            #pragma unroll
            for (int r = 0; r < 4; r++)
                Xo[(size_t)(m0 + rl + r) * CT + n] = f2b(acc[i][j][r]);
        }
    }
}

extern "C" void kernel_launch(void* const* d_in, const int* in_sizes, int n_in,
                              void* d_out, int out_size, void* d_ws, size_t ws_size,
                              hipStream_t stream) {
    const float* x_enc  = (const float*)d_in[0];
    const float* x_mark = (const float*)d_in[1];
    const float* norm_w = (const float*)d_in[4];
    const float* inp_W  = (const float*)d_in[5];
    const float* inp_b  = (const float*)d_in[6];
    const float* conv_W = (const float*)d_in[7];
    const float* conv_b = (const float*)d_in[8];
    const float* convlin_W = (const float*)d_in[9];
    const float* convlin_b = (const float*)d_in[10];
    const float* fc1_W = (const float*)d_in[11];
    const float* fc1_b = (const float*)d_in[12];
    const float* fc2_W = (const float*)d_in[13];
    const float* fc2_b = (const float*)d_in[14];
    const float* fc3_W = (const float*)d_in[15];
    const float* fc3_b = (const float*)d_in[16];
    const float* D_W   = (const float*)d_in[17];
    const float* D_b   = (const float*)d_in[18];
    const float* out_W = (const float*)d_in[19];
    const float* out_b = (const float*)d_in[20];
    const float* proj_W = (const float*)d_in[21];
    const float* proj_b = (const float*)d_in[22];

    // ---- workspace layout ----
    char* ws = (char*)d_ws;
    float* MEANS = (float*)(ws);
    float* STDEV = (float*)(ws + 65536);
    float* CBv   = (float*)(ws + 131072);
    float* SCL   = (float*)(ws + 196608);    // 64 KB slot (16384 fp32)
    bf16* wt = (bf16*)(ws + 262144);
    bf16* wt_g1      = wt;                   // 3 x [1024][256]  (nw-folded inp^T | D^T)
    bf16* wt_g3      = wt + 786432;          // 3 x [fc1^T | fc2⊕fc3]
    bf16* wt_convlin = wt + 2359296;
    bf16* wt_out     = wt + 3145728;
    bf16* wt_proj    = wt + 3538944;
    bf16* wt_conv    = wt + 3604480;         // 3 x [3][512][512]
    bf16* xpT = (bf16*)(ws + 12189696);      // [32][528][512]
    const size_t POOLB = 16777216;
    bf16* pool[4] = {
        (bf16*)(ws + 29491200),
        (bf16*)(ws + 29491200 + POOLB),
        (bf16*)(ws + 29491200 + 2 * POOLB),
        (bf16*)(ws + 29491200 + 3 * POOLB),
    };
    float* out = (float*)d_out;

    // ---- single merged prepack (weights + conv + pads + CBv zero) ----
    P8 p;
    p.s[0] = inp_W;  p.d[0] = wt_g1;
    p.s[1] = D_W;    p.d[1] = wt_g1 + 131072;
    p.s[2] = fc1_W;  p.d[2] = wt_g3;
    p.s[3] = fc2_W;  p.d[3] = wt_g3 + 262144;
    p.s[4] = fc3_W;  p.d[4] = wt_g3 + 262144;
    p.s[5] = convlin_W; p.d[5] = wt_convlin;
    p.s[6] = out_W;  p.d[6] = wt_out;
    p.s[7] = proj_W; p.d[7] = wt_proj;
    int tailBlocks = (CONV3 + 32768 + MROWS + 255) / 256;
    prepack_all_kernel<<<MTILES + tailBlocks, 256, 0, stream>>>(
        p, norm_w, conv_W, wt_conv, xpT, CBv);

    // ---- stats + build: raw x -> pool[0].lo, rms scale -> SCL ----
    buildx_kernel<<<256, 256, 0, stream>>>(x_enc, x_mark, MEANS, STDEV, pool[0], SCL);

    // 4-pool rotation
    int ia = 0, ico = 1, ires = 2, iout = 3;
    for (int i = 0; i < 3; i++) {
        bf16* A  = pool[ia];
        bf16* XCO = pool[ico];
        bf16* XRES = pool[ires];
        bf16* OUTP = pool[iout];

        // [xp|xres] = (x*scl) @ [nw∘inp | nw∘D] + b : xp -> xpT^T, xres -> XRES
        g64_kernel<4><<<dim3(128, 16), 256, 0, stream>>>(
            A, wt_g1 + (size_t)i * 262144, 256, inp_b + i * CT2, D_b + i * CT2, SCL,
            nullptr, nullptr, nullptr, xpT, XRES, 1024, nullptr, nullptr, nullptr);
        // xc = silu(conv(xp)) -> A ; zeroes CBv
        conv_mfma_kernel<<<2048, 256, 0, stream>>>(wt_conv + (size_t)i * 786432, xpT,
                                                   conv_b + i * CF, A, CBv);
        // xco = xc @ convlin + b -> XCO
        g64_kernel<0><<<dim3(128, 8), 256, 0, stream>>>(
            A, wt_convlin + (size_t)i * 262144, 512, convlin_b + i * CT2, nullptr, nullptr,
            nullptr, nullptr, nullptr, XCO, nullptr, 512, nullptr, nullptr, nullptr);
        // cb atomics
        g64_kernel<1><<<dim3(128, 8), 256, 0, stream>>>(
            XCO, wt_g3 + (size_t)i * 524288 + 262144, 512, fc2_b + i * CT, fc3_b + i * CT,
            nullptr, nullptr, nullptr, CBv, nullptr, nullptr, 0, nullptr, nullptr, nullptr);
        // g = gate(fc1, xco, cb, xres) -> A
        g64_kernel<2><<<dim3(128, 8), 256, 0, stream>>>(
            XCO, wt_g3 + (size_t)i * 524288, 512, fc1_b + i * CT2, nullptr, nullptr,
            CBv, XRES, nullptr, A, nullptr, 512, nullptr, nullptr, nullptr);
        // x_next = g @ out_W + b -> OUTP.lo ; scl -> SCL
        gemm_scl_kernel<<<512, 256, 0, stream>>>(
            A, wt_out + (size_t)i * 131072, out_b + i * CT, OUTP, SCL);

        int na = iout, nco = ia, nres = ico, nout = ires;
        ia = na; ico = nco; ires = nres; iout = nout;
    }

    // x_final in pool[ia].lo. dec = x @ proj_W + b, de-norm + transpose to out
    g64_kernel<3><<<dim3(128, 4), 256, 0, stream>>>(
        pool[ia], wt_proj, 256, proj_b, nullptr, nullptr, nullptr, nullptr, nullptr,
        nullptr, nullptr, 0, MEANS, STDEV, out);
}

// Round 5
// 513.867 us; speedup vs baseline: 1.1499x; 1.1499x over previous
//
#include <hip/hip_runtime.h>
#include <hip/hip_bf16.h>
#include <math.h>

typedef __hip_bfloat16 bf16;
typedef short short8 __attribute__((ext_vector_type(8)));
typedef short short4v __attribute__((ext_vector_type(4)));
typedef float floatx4 __attribute__((ext_vector_type(4)));

constexpr int CB_ = 32;
constexpr int CT = 256;
constexpr int CF = 512;
constexpr int CN = 508;
constexpr int CM = 4;
constexpr int CT2 = 512;
constexpr int MROWS = CB_ * CF;  // 16384
constexpr int PADL = 528;

__device__ __forceinline__ float b2f(bf16 v) { return __bfloat162float(v); }
__device__ __forceinline__ bf16 f2b(float v) { return __float2bfloat16(v); }
__device__ __forceinline__ float s2f(short s) {
    unsigned u = ((unsigned)(unsigned short)s) << 16;
    return __builtin_bit_cast(float, u);
}
__device__ __forceinline__ short f2s(float v) {
    bf16 t = __float2bfloat16(v);
    return __builtin_bit_cast(short, t);
}
__device__ __forceinline__ float silu_f(float x) { return x / (1.0f + __expf(-x)); }
__device__ __forceinline__ float softplus_f(float x) {
    return fmaxf(x, 0.0f) + __logf(1.0f + __expf(-fabsf(x)));
}

__device__ __forceinline__ void gl_lds16(const bf16* g, short* l) {
    __builtin_amdgcn_global_load_lds(
        (const __attribute__((address_space(1))) unsigned int*)(g),
        (__attribute__((address_space(3))) unsigned int*)(l), 16, 0, 0);
}

// BK=64 LDS tiles: [rows][64 shorts] (128B rows). gl_lds16 covers 8 rows x 64 cols.
// XOR swizzle: LDS slot (row, col16) holds global (row, col16 ^ (row&7)).
// Source addr per lane: row += lane>>3 ; col16 = (lane&7) ^ (lane>>3).
// ds_read col16' = (s*4+quad) ^ (row&7) recovers k = s*32 + quad*8.
// SINGLE-buffered (R4 dbuf regressed: LDS x2 halved blocks/CU; TLP > pipelining).

// ---- ALL prepack in one kernel: 8 weight transposes (+nw folding for inp/D),
// conv weight pack (float3/thread, coalesced), xpT pad rows, CBv zero.
constexpr int CONV3 = 3 * 512 * 512;  // 786432 (ib,co,ci) triples
constexpr int MTILES = 3520;
struct P8 { const float* s[8]; bf16* d[8]; };
__global__ __launch_bounds__(256) void prepack_all_kernel(P8 p, const float* __restrict__ nw,
                                                          const float* __restrict__ convW,
                                                          bf16* __restrict__ convD,
                                                          bf16* __restrict__ xpT,
                                                          float* __restrict__ CBv) {
    int bid = blockIdx.x;
    if (bid >= MTILES) {
        int idx = (bid - MTILES) * 256 + threadIdx.x;
        if (idx < CONV3) {
            int ci = idx & 511;
            int co = (idx >> 9) & 511;
            int ib = idx >> 18;
            const float* src = convW + ((size_t)(ib * 512 + co) * 512 + ci) * 3;
            #pragma unroll
            for (int t = 0; t < 3; t++)
                convD[(((size_t)(ib * 3 + t) * 512 + co) << 9) + ci] = f2b(src[t]);
        } else if (idx < CONV3 + 32768) {
            int j = idx - CONV3;
            int ci = j & 511;
            int w = (j >> 9) & 1;
            int b = j >> 10;
            xpT[((size_t)b * PADL + (w ? 513 : 0)) * 512 + ci] = f2b(0.0f);
        } else if (idx < CONV3 + 32768 + MROWS) {
            CBv[idx - CONV3 - 32768] = 0.0f;
        }
        return;
    }
    const int Ks[8]   = {256, 256, 512, 512, 512, 512, 512, 256};
    const int Ns[8]   = {512, 512, 512, 256, 256, 512, 256, 256};
    const int zs[8]   = {3, 3, 3, 3, 3, 3, 3, 1};
    const int dstr[8] = {262144, 262144, 524288, 524288, 524288, 262144, 131072, 65536};
    const int rml[8]  = {1, 1, 1, 2, 2, 1, 1, 1};
    const int rad[8]  = {0, 0, 0, 0, 1, 0, 0, 0};
    int m = 0, acc = 0;
    for (m = 0; m < 8; m++) {
        int c = (Ns[m] >> 5) * (Ks[m] >> 5) * zs[m];
        if (bid < acc + c) break;
        acc += c;
    }
    int lid = bid - acc;
    int K = Ks[m], N = Ns[m];
    int tx = N >> 5, ty = K >> 5;
    int z = lid / (tx * ty), rem = lid % (tx * ty);
    int k0 = (rem / tx) * 32, n0 = (rem % tx) * 32;
    const float* s = p.s[m] + (size_t)z * K * N;
    bf16* d = p.d[m] + (size_t)z * dstr[m];
    int mul = rml[m], add = rad[m];
    bool fold = (m <= 1);  // inp_W, D_W: fold nw_z into K-rows
    __shared__ float Ts[32][33];
    for (int e = threadIdx.x; e < 1024; e += 256) {
        int r = e >> 5, c = e & 31;
        float v = s[(size_t)(k0 + r) * N + n0 + c];
        if (fold) v *= nw[z * 256 + k0 + r];
        Ts[r][c] = v;
    }
    __syncthreads();
    for (int e = threadIdx.x; e < 1024; e += 256) {
        int r = e >> 5, c = e & 31;
        d[(size_t)((n0 + r) * mul + add) * K + k0 + c] = f2b(Ts[c][r]);
    }
}

// ---- fused stats + build_x (iter 0): writes RAW x (bf16) + rms scale SCL ----
__global__ __launch_bounds__(256) void buildx_kernel(
    const float* __restrict__ xe, const float* __restrict__ xm,
    float* __restrict__ means, float* __restrict__ stdev,
    bf16* __restrict__ X0, float* __restrict__ SCL) {
    __shared__ float L[256][65];
    __shared__ float red_s[4][64], red_q[4][64];
    __shared__ float stat_m[64], stat_i[64];
    int blk = blockIdx.x;
    int b = blk >> 3, f0 = (blk & 7) * 64;
    int tid = threadIdx.x;
    int j = tid & 63, tq = tid >> 6;
    int f = f0 + j;
    float ps = 0.f, pq = 0.f;
    const float* xep = xe + (size_t)b * CT * CN + f;
    const float* xmp = xm + (size_t)b * CT * CM + (f - CN);
    #pragma unroll 4
    for (int tt = 0; tt < 64; tt++) {
        int t = tq * 64 + tt;
        float v = (f < CN) ? xep[(size_t)t * CN] : xmp[(size_t)t * CM];
        L[t][j] = v;
        ps += v;
        pq += v * v;
    }
    red_s[tq][j] = ps;
    red_q[tq][j] = pq;
    __syncthreads();
    if (tid < 64) {
        int ff = f0 + tid;
        float s = red_s[0][tid] + red_s[1][tid] + red_s[2][tid] + red_s[3][tid];
        float q = red_q[0][tid] + red_q[1][tid] + red_q[2][tid] + red_q[3][tid];
        float mean, isd, msq;
        if (ff < CN) {
            mean = s * (1.0f / 256.0f);
            float var = fmaxf(q * (1.0f / 256.0f) - mean * mean, 0.0f);
            float sd = sqrtf(var + 1e-5f);
            isd = 1.0f / sd;
            means[b * CN + ff] = mean;
            stdev[b * CN + ff] = sd;
            msq = var / (var + 1e-5f);
        } else {
            mean = 0.0f;
            isd = 1.0f;
            msq = q * (1.0f / 256.0f);
        }
        stat_m[tid] = mean;
        stat_i[tid] = isd;
        SCL[b * 512 + ff] = rsqrtf(msq + 1e-5f);
    }
    __syncthreads();
    bf16* outp = X0 + ((size_t)(b * 512 + f0)) * 256;
    int t = tid;
    #pragma unroll 4
    for (int fp = 0; fp < 64; fp++) {
        float val = (L[t][fp] - stat_m[fp]) * stat_i[fp];
        outp[(size_t)fp * 256 + t] = f2b(val);
    }
}

// ---- unified 128x64-tile GEMM, BK=64, single-buffered (24KB LDS, 4 blk/CU).
// EPI 0: plain store (+b1). EPI 3: proj de-norm fp32 out.
// EPI 4: [inp|D]: n0<512 -> xpT scatter (b1, SCL); else silu->o2 (b2, SCL).
// EPI 5: [fc1 | fc2(+)fc3]: n0<512 -> P=softplus(acc+b1)*xco -> outf (fp32);
//        n0>=512 -> cb pair-product atomics (b2=fc2_b, CBin=fc3_b) -> CBout. ----
template <int EPI>
__global__ __launch_bounds__(256) void g64_kernel(const bf16* __restrict__ A,
                                                  const bf16* __restrict__ Wt,
                                                  int K,
                                                  const float* __restrict__ b1,
                                                  const float* __restrict__ b2,
                                                  const float* __restrict__ SCL,
                                                  const float* __restrict__ CBin,
                                                  float* __restrict__ CBout,
                                                  bf16* __restrict__ o1,
                                                  bf16* __restrict__ o2,
                                                  int Ncols,
                                                  const float* __restrict__ means,
                                                  const float* __restrict__ stdev,
                                                  float* __restrict__ outf) {
    __shared__ __align__(16) short As[128 * 64];
    __shared__ __align__(16) short Bs[64 * 64];
    const int tid = threadIdx.x;
    const int lane = tid & 63;
    const int wave = tid >> 6;
    const int m0 = blockIdx.x * 128, n0 = blockIdx.y * 64;

    const int lrow8 = lane >> 3;
    const int lcolS = (((lane & 7) ^ lrow8) << 3);
    const int wm = (wave & 1) * 64, wn = (wave >> 1) * 32;
    const int fr = lane & 15, quad = lane >> 4;
    const int fr7 = fr & 7;

    floatx4 acc[4][2];
    #pragma unroll
    for (int i = 0; i < 4; i++)
        #pragma unroll
        for (int j = 0; j < 2; j++) acc[i][j] = (floatx4){0.f, 0.f, 0.f, 0.f};

    for (int k0 = 0; k0 < K; k0 += 64) {
        for (int ca = wave; ca < 16; ca += 4)
            gl_lds16(A + (size_t)(m0 + ca * 8 + lrow8) * K + k0 + lcolS, &As[ca * 512]);
        for (int cb = wave; cb < 8; cb += 4)
            gl_lds16(Wt + (size_t)(n0 + cb * 8 + lrow8) * K + k0 + lcolS, &Bs[cb * 512]);
        __syncthreads();
        #pragma unroll
        for (int s = 0; s < 2; s++) {
            const int co = (((s * 4 + quad) ^ fr7) << 3);
            short8 af[4], bfv[2];
            #pragma unroll
            for (int i = 0; i < 4; i++) af[i] = *(const short8*)&As[(wm + i * 16 + fr) * 64 + co];
            #pragma unroll
            for (int j = 0; j < 2; j++) bfv[j] = *(const short8*)&Bs[(wn + j * 16 + fr) * 64 + co];
            #pragma unroll
            for (int i = 0; i < 4; i++)
                #pragma unroll
                for (int j = 0; j < 2; j++)
                    acc[i][j] = __builtin_amdgcn_mfma_f32_16x16x32_bf16(af[i], bfv[j], acc[i][j], 0, 0, 0);
        }
        __syncthreads();
    }

    if (EPI == 0) {
        #pragma unroll
        for (int j = 0; j < 2; j++) {
            int n = n0 + wn + j * 16 + fr;
            float bv = b1[n];
            #pragma unroll
            for (int i = 0; i < 4; i++) {
                int mb = m0 + wm + i * 16 + quad * 4;
                #pragma unroll
                for (int r = 0; r < 4; r++)
                    o1[(size_t)(mb + r) * Ncols + n] = f2b(acc[i][j][r] + bv);
            }
        }
    } else if (EPI == 3) {  // proj + de-norm + transpose, fp32 out
        #pragma unroll
        for (int j = 0; j < 2; j++) {
            int t = n0 + wn + j * 16 + fr;
            float bv = b1[t];
            #pragma unroll
            for (int i = 0; i < 4; i++) {
                int mb = m0 + wm + i * 16 + quad * 4;
                int b = mb >> 9;
                int nv = mb & 511;
                if (nv < CN) {
                    floatx4 o;
                    #pragma unroll
                    for (int r = 0; r < 4; r++) {
                        int sn = b * CN + nv + r;
                        o[r] = (acc[i][j][r] + bv) * stdev[sn] + means[sn];
                    }
                    *(floatx4*)(outf + ((size_t)(b * CT + t)) * CN + nv) = o;
                }
            }
        }
    } else if (EPI == 4) {  // [inp|D] with per-row rms scale
        if (n0 < 512) {
            int b = (m0 + wm) >> 9;
            #pragma unroll
            for (int i = 0; i < 4; i++) {
                int mb = m0 + wm + i * 16 + quad * 4;
                float sclr[4];
                #pragma unroll
                for (int r = 0; r < 4; r++) sclr[r] = SCL[mb + r];
                int ci = mb & 511;
                #pragma unroll
                for (int j = 0; j < 2; j++) {
                    int n = n0 + wn + j * 16 + fr;
                    float bv = b1[n];
                    bf16* dst = o1 + ((size_t)b * PADL + n + 1) * 512;
                    short4v pk;
                    #pragma unroll
                    for (int r = 0; r < 4; r++) pk[r] = f2s(acc[i][j][r] * sclr[r] + bv);
                    *(short4v*)(dst + ci) = pk;
                }
            }
        } else {
            #pragma unroll
            for (int i = 0; i < 4; i++) {
                int mb = m0 + wm + i * 16 + quad * 4;
                float sclr[4];
                #pragma unroll
                for (int r = 0; r < 4; r++) sclr[r] = SCL[mb + r];
                #pragma unroll
                for (int j = 0; j < 2; j++) {
                    int n = n0 + wn + j * 16 + fr;
                    float bv = b2[n - 512];
                    #pragma unroll
                    for (int r = 0; r < 4; r++)
                        o2[(size_t)(mb + r) * 512 + (n - 512)] =
                            f2b(silu_f(acc[i][j][r] * sclr[r] + bv));
                }
            }
        }
    } else if (EPI == 5) {  // [fc1 | cb]
        if (n0 < 512) {
            #pragma unroll
            for (int i = 0; i < 4; i++) {
                int mb = m0 + wm + i * 16 + quad * 4;
                #pragma unroll
                for (int j = 0; j < 2; j++) {
                    int n = n0 + wn + j * 16 + fr;
                    float bv = b1[n];
                    #pragma unroll
                    for (int r = 0; r < 4; r++) {
                        size_t off = (size_t)(mb + r) * 512 + n;
                        float delta = softplus_f(acc[i][j][r] + bv);
                        outf[off] = delta * b2f(A[off]);
                    }
                }
            }
        } else {
            float bv[2];
            #pragma unroll
            for (int j = 0; j < 2; j++) {
                int nn = n0 + wn + j * 16 + fr - 512;
                int c = nn >> 1;
                bv[j] = (fr & 1) ? CBin[c] : b2[c];
            }
            #pragma unroll
            for (int i = 0; i < 4; i++) {
                #pragma unroll
                for (int r = 0; r < 4; r++) {
                    float s = 0.f;
                    #pragma unroll
                    for (int j = 0; j < 2; j++) {
                        float v = acc[i][j][r] + bv[j];
                        s += v * __shfl_xor(v, 1);
                    }
                    s += __shfl_xor(s, 2);
                    s += __shfl_xor(s, 4);
                    s += __shfl_xor(s, 8);
                    if (fr == 0)
                        atomicAdd(&CBout[m0 + wm + i * 16 + quad * 4 + r], s * 0.5f);
                }
            }
        }
    }
}

// ---- conv as implicit MFMA GEMM, 64x64 tile single-buffered (33KB, 4 blk/CU),
// grid 2048. Zeroes CBv at entry. ----
__global__ __launch_bounds__(256) void conv_mfma_kernel(const bf16* __restrict__ Wc,
                                                        const bf16* __restrict__ xpT,
                                                        const float* __restrict__ bias,
                                                        bf16* __restrict__ Out,
                                                        float* __restrict__ CBvZ) {
    __shared__ __align__(16) short As[3 * 64 * 64];
    __shared__ __align__(16) short Bs[72 * 64];
    const int tid = threadIdx.x;
    const int lane = tid & 63;
    const int wave = tid >> 6;
    int bx = blockIdx.x;
    if (bx < 128 && tid < 128) CBvZ[bx * 128 + tid] = 0.0f;
    int b = bx >> 6, rem = bx & 63;
    int mt = rem >> 3, nt = rem & 7;
    const int m0 = mt * 64, n0 = nt * 64;
    const bf16* xb = xpT + (size_t)b * PADL * 512;

    const int lrow8 = lane >> 3;
    const int lcolS = (((lane & 7) ^ lrow8) << 3);
    const int wm = (wave & 1) * 32, wn = (wave >> 1) * 32;
    const int fr = lane & 15, quad = lane >> 4;
    const int fr7 = fr & 7;

    floatx4 acc[2][2];
    #pragma unroll
    for (int i = 0; i < 2; i++)
        #pragma unroll
        for (int j = 0; j < 2; j++) acc[i][j] = (floatx4){0.f, 0.f, 0.f, 0.f};

    for (int k0 = 0; k0 < 512; k0 += 64) {
        for (int ga = wave; ga < 24; ga += 4) {
            int tap = ga >> 3, rg = ga & 7;
            gl_lds16(Wc + (size_t)tap * 262144 + (size_t)(m0 + rg * 8 + lrow8) * 512 + k0 + lcolS,
                     &As[tap * 4096 + rg * 512]);
        }
        for (int gb = wave; gb < 9; gb += 4) {
            gl_lds16(xb + (size_t)(n0 + gb * 8 + lrow8) * 512 + k0 + lcolS, &Bs[gb * 512]);
        }
        __syncthreads();
        #pragma unroll
        for (int s = 0; s < 2; s++) {
            const int sq = s * 4 + quad;
            #pragma unroll
            for (int tap = 0; tap < 3; tap++) {
                const int coA = ((sq ^ fr7) << 3);
                const int coB = ((sq ^ ((fr + tap) & 7)) << 3);
                short8 af[2], bfv[2];
                #pragma unroll
                for (int i = 0; i < 2; i++)
                    af[i] = *(const short8*)&As[tap * 4096 + (wm + i * 16 + fr) * 64 + coA];
                #pragma unroll
                for (int j = 0; j < 2; j++)
                    bfv[j] = *(const short8*)&Bs[(wn + j * 16 + fr + tap) * 64 + coB];
                #pragma unroll
                for (int i = 0; i < 2; i++)
                    #pragma unroll
                    for (int j = 0; j < 2; j++)
                        acc[i][j] = __builtin_amdgcn_mfma_f32_16x16x32_bf16(af[i], bfv[j], acc[i][j], 0, 0, 0);
            }
        }
        __syncthreads();
    }
    bf16* ob = Out + (size_t)b * CF * CT2;
    #pragma unroll
    for (int i = 0; i < 2; i++) {
        int mb = m0 + wm + i * 16 + quad * 4;
        #pragma unroll
        for (int r = 0; r < 4; r++) {
            float bv = bias[mb + r];
            #pragma unroll
            for (int j = 0; j < 2; j++) {
                int n = n0 + wn + j * 16 + fr;
                ob[(size_t)(mb + r) * CT2 + n] = f2b(silu_f(acc[i][j][r] + bv));
            }
        }
    }
}

// ---- out-GEMM (K=512, N=256) with FUSED gate on the A-stage:
// G[m][k] = silu(P[m][k]*cb[m]) * xres[m][k], computed in regs -> LDS (never HBM).
// Also computes rms scale SCL. M-tile 32, grid 512, single-buffered. ----
__global__ __launch_bounds__(256) void gemm_scl_gate_kernel(const float* __restrict__ P,
                                                            const bf16* __restrict__ Xres,
                                                            const float* __restrict__ CBv,
                                                            const bf16* __restrict__ Wt,
                                                            const float* __restrict__ bias,
                                                            bf16* __restrict__ Xo,
                                                            float* __restrict__ SCL) {
    __shared__ __align__(16) short As[32 * 64];
    __shared__ __align__(16) short Bs[256 * 64];
    __shared__ float red[4][32];
    const int tid = threadIdx.x;
    const int lane = tid & 63;
    const int wave = tid >> 6;
    const int m0 = blockIdx.x * 32;

    const int lrow8 = lane >> 3;
    const int lcolS = (((lane & 7) ^ lrow8) << 3);
    const int wn = wave * 64;
    const int fr = lane & 15, quad = lane >> 4;
    const int fr7 = fr & 7;

    floatx4 acc[2][4];
    #pragma unroll
    for (int i = 0; i < 2; i++)
        #pragma unroll
        for (int j = 0; j < 4; j++) acc[i][j] = (floatx4){0.f, 0.f, 0.f, 0.f};

    const int arow = m0 + wave * 8 + lrow8;   // each wave owns 8 A-rows
    const float cbr = CBv[arow];

    for (int k0 = 0; k0 < 512; k0 += 64) {
        for (int c = wave; c < 32; c += 4)
            gl_lds16(Wt + (size_t)(c * 8 + lrow8) * 512 + k0 + lcolS, &Bs[c * 512]);
        {
            int col = k0 + lcolS;
            const float* pp = P + (size_t)arow * 512 + col;
            floatx4 p0 = *(const floatx4*)pp;
            floatx4 p1 = *(const floatx4*)(pp + 4);
            short8 xr = *(const short8*)(Xres + (size_t)arow * 512 + col);
            short8 g;
            #pragma unroll
            for (int e = 0; e < 4; e++) {
                g[e] = f2s(silu_f(p0[e] * cbr) * s2f(xr[e]));
                g[4 + e] = f2s(silu_f(p1[e] * cbr) * s2f(xr[4 + e]));
            }
            *(short8*)&As[wave * 512 + lrow8 * 64 + (lane & 7) * 8] = g;
        }
        __syncthreads();
        #pragma unroll
        for (int s = 0; s < 2; s++) {
            const int co = (((s * 4 + quad) ^ fr7) << 3);
            short8 af[2], bfv[4];
            #pragma unroll
            for (int i = 0; i < 2; i++) af[i] = *(const short8*)&As[(i * 16 + fr) * 64 + co];
            #pragma unroll
            for (int j = 0; j < 4; j++) bfv[j] = *(const short8*)&Bs[(wn + j * 16 + fr) * 64 + co];
            #pragma unroll
            for (int i = 0; i < 2; i++)
                #pragma unroll
                for (int j = 0; j < 4; j++)
                    acc[i][j] = __builtin_amdgcn_mfma_f32_16x16x32_bf16(af[i], bfv[j], acc[i][j], 0, 0, 0);
        }
        __syncthreads();
    }
    #pragma unroll
    for (int j = 0; j < 4; j++) {
        float bv = bias[wn + j * 16 + fr];
        #pragma unroll
        for (int i = 0; i < 2; i++)
            #pragma unroll
            for (int r = 0; r < 4; r++) acc[i][j][r] += bv;
    }
    #pragma unroll
    for (int i = 0; i < 2; i++) {
        #pragma unroll
        for (int r = 0; r < 4; r++) {
            float s = 0.f;
            #pragma unroll
            for (int j = 0; j < 4; j++) s += acc[i][j][r] * acc[i][j][r];
            #pragma unroll
            for (int o = 8; o > 0; o >>= 1) s += __shfl_xor(s, o);
            if (fr == 0) red[wave][i * 16 + quad * 4 + r] = s;
        }
    }
    __syncthreads();
    if (tid < 32) {
        float tot = red[0][tid] + red[1][tid] + red[2][tid] + red[3][tid];
        SCL[m0 + tid] = rsqrtf(tot * (1.0f / CT) + 1e-5f);
    }
    #pragma unroll
    for (int j = 0; j < 4; j++) {
        int n = wn + j * 16 + fr;
        #pragma unroll
        for (int i = 0; i < 2; i++) {
            int rl = i * 16 + quad * 4;
            #pragma unroll
            for (int r = 0; r < 4; r++)
                Xo[(size_t)(m0 + rl + r) * CT + n] = f2b(acc[i][j][r]);
        }
    }
}

extern "C" void kernel_launch(void* const* d_in, const int* in_sizes, int n_in,
                              void* d_out, int out_size, void* d_ws, size_t ws_size,
                              hipStream_t stream) {
    const float* x_enc  = (const float*)d_in[0];
    const float* x_mark = (const float*)d_in[1];
    const float* norm_w = (const float*)d_in[4];
    const float* inp_W  = (const float*)d_in[5];
    const float* inp_b  = (const float*)d_in[6];
    const float* conv_W = (const float*)d_in[7];
    const float* conv_b = (const float*)d_in[8];
    const float* convlin_W = (const float*)d_in[9];
    const float* convlin_b = (const float*)d_in[10];
    const float* fc1_W = (const float*)d_in[11];
    const float* fc1_b = (const float*)d_in[12];
    const float* fc2_W = (const float*)d_in[13];
    const float* fc2_b = (const float*)d_in[14];
    const float* fc3_W = (const float*)d_in[15];
    const float* fc3_b = (const float*)d_in[16];
    const float* D_W   = (const float*)d_in[17];
    const float* D_b   = (const float*)d_in[18];
    const float* out_W = (const float*)d_in[19];
    const float* out_b = (const float*)d_in[20];
    const float* proj_W = (const float*)d_in[21];
    const float* proj_b = (const float*)d_in[22];

    // ---- workspace layout ----
    char* ws = (char*)d_ws;
    float* MEANS = (float*)(ws);
    float* STDEV = (float*)(ws + 65536);
    float* CBv   = (float*)(ws + 131072);
    float* SCL   = (float*)(ws + 196608);    // 64 KB slot (16384 fp32)
    bf16* wt = (bf16*)(ws + 262144);
    bf16* wt_g1      = wt;                   // 3 x [1024][256]  (nw-folded inp^T | D^T)
    bf16* wt_g3      = wt + 786432;          // 3 x [fc1^T(512r) | fc2(+)fc3(512r)] K=512
    bf16* wt_convlin = wt + 2359296;
    bf16* wt_out     = wt + 3145728;
    bf16* wt_proj    = wt + 3538944;
    bf16* wt_conv    = wt + 3604480;         // 3 x [3][512][512]
    bf16* xpT = (bf16*)(ws + 12189696);      // [32][528][512]
    const size_t POOLB = 16777216;
    bf16* X    = (bf16*)(ws + 29491200);
    bf16* XRES = (bf16*)(ws + 29491200 + POOLB);
    bf16* XC   = (bf16*)(ws + 29491200 + 2 * POOLB);
    bf16* XCO  = (bf16*)(ws + 29491200 + 3 * POOLB);
    float* Pf  = (float*)(ws + 29491200 + 4 * POOLB);  // [16384][512] fp32 (33.5MB)
    float* out = (float*)d_out;

    // ---- single merged prepack (weights + conv + pads + CBv zero) ----
    P8 p;
    p.s[0] = inp_W;  p.d[0] = wt_g1;
    p.s[1] = D_W;    p.d[1] = wt_g1 + 131072;
    p.s[2] = fc1_W;  p.d[2] = wt_g3;
    p.s[3] = fc2_W;  p.d[3] = wt_g3 + 262144;
    p.s[4] = fc3_W;  p.d[4] = wt_g3 + 262144;
    p.s[5] = convlin_W; p.d[5] = wt_convlin;
    p.s[6] = out_W;  p.d[6] = wt_out;
    p.s[7] = proj_W; p.d[7] = wt_proj;
    int tailBlocks = (CONV3 + 32768 + MROWS + 255) / 256;
    prepack_all_kernel<<<MTILES + tailBlocks, 256, 0, stream>>>(
        p, norm_w, conv_W, wt_conv, xpT, CBv);

    // ---- stats + build: raw x -> X, rms scale -> SCL ----
    buildx_kernel<<<256, 256, 0, stream>>>(x_enc, x_mark, MEANS, STDEV, X, SCL);

    for (int i = 0; i < 3; i++) {
        // [xp|xres] = (x*scl) @ [nw.inp | nw.D] + b : xp -> xpT^T, xres -> XRES
        g64_kernel<4><<<dim3(128, 16), 256, 0, stream>>>(
            X, wt_g1 + (size_t)i * 262144, 256, inp_b + i * CT2, D_b + i * CT2, SCL,
            nullptr, nullptr, xpT, XRES, 1024, nullptr, nullptr, nullptr);
        // xc = silu(conv(xp)) -> XC ; zeroes CBv
        conv_mfma_kernel<<<2048, 256, 0, stream>>>(wt_conv + (size_t)i * 786432, xpT,
                                                   conv_b + i * CF, XC, CBv);
        // xco = xc @ convlin + b -> XCO
        g64_kernel<0><<<dim3(128, 8), 256, 0, stream>>>(
            XC, wt_convlin + (size_t)i * 262144, 512, convlin_b + i * CT2, nullptr, nullptr,
            nullptr, nullptr, XCO, nullptr, 512, nullptr, nullptr, nullptr);
        // merged [fc1 | cb]: P = softplus(fc1)*xco -> Pf ; cb atomics -> CBv
        g64_kernel<5><<<dim3(128, 16), 256, 0, stream>>>(
            XCO, wt_g3 + (size_t)i * 524288, 512, fc1_b + i * CT2, fc2_b + i * CT, nullptr,
            fc3_b + i * CT, CBv, nullptr, nullptr, 0, nullptr, nullptr, Pf);
        // x_next = gate(P,cb,xres) @ out_W + b -> X ; scl -> SCL
        gemm_scl_gate_kernel<<<512, 256, 0, stream>>>(
            Pf, XRES, CBv, wt_out + (size_t)i * 131072, out_b + i * CT, X, SCL);
    }

    // dec = x @ proj_W + b, de-norm + transpose to out
    g64_kernel<3><<<dim3(128, 4), 256, 0, stream>>>(
        X, wt_proj, 256, proj_b, nullptr, nullptr, nullptr, nullptr, nullptr,
        nullptr, 0, MEANS, STDEV, out);
}